// Round 4
// baseline (119.337 us; speedup 1.0000x reference)
//
#include <hip/hip_runtime.h>

// Problem constants (from reference)
#define S0d   256
#define S1d   256
#define BONDd 32
#define BATCHd 2048
#define UNITSd 65536        // S0 * S1
#define UCH   4096          // units per block (256 thr x 4 x f32x4)
#define NB    32            // batches per block

typedef float f32x4 __attribute__((ext_vector_type(4)));
typedef float f32x2 __attribute__((ext_vector_type(2)));

// ---------------------------------------------------------------------------
// Kernel A: G_j[a*256+c] = sum_p (core1[0,a,p]+core1[1,a,p]) * core2[j,c,p]
// G layout in d_ws: G0[65536] then G1[65536]
// ---------------------------------------------------------------------------
__global__ __launch_bounds__(256) void precompute_G(
    const float* __restrict__ core1, const float* __restrict__ core2,
    float* __restrict__ G) {
  const int u = blockIdx.x * 256 + threadIdx.x;   // 0..65535
  const int a = u >> 8;
  const int c = u & 255;
  const f32x4* c10 = (const f32x4*)(core1 + a * BONDd);                 // core1[0,a,:]
  const f32x4* c11 = (const f32x4*)(core1 + S0d * BONDd + a * BONDd);   // core1[1,a,:]
  const f32x4* r0  = (const f32x4*)(core2 + c * BONDd);                 // core2[0,c,:]
  const f32x4* r1  = (const f32x4*)(core2 + S1d * BONDd + c * BONDd);   // core2[1,c,:]
  float acc0 = 0.f, acc1 = 0.f;
#pragma unroll
  for (int q = 0; q < BONDd / 4; ++q) {
    f32x4 x = c10[q], y = c11[q];
    f32x4 s = x + y;
    f32x4 v0 = r0[q], v1 = r1[q];
    acc0 = fmaf(s.x, v0.x, fmaf(s.y, v0.y, fmaf(s.z, v0.z, fmaf(s.w, v0.w, acc0))));
    acc1 = fmaf(s.x, v1.x, fmaf(s.y, v1.y, fmaf(s.z, v1.z, fmaf(s.w, v1.w, acc1))));
  }
  G[u] = acc0;
  G[UNITSd + u] = acc1;
}

// ---------------------------------------------------------------------------
// Kernel B (register-tiled): block = (4096-unit slice) x (32 batches).
// G0/G1/bias slice lives in 48 VGPRs, loaded ONCE; inner loop over batches
// emits 16 KiB-contiguous nontemporal store bursts. L2 reads ~48 MiB total.
// ---------------------------------------------------------------------------
__global__ __launch_bounds__(256) void td_tile(
    const float* __restrict__ inputs, const float* __restrict__ G,
    const float* __restrict__ bias, float* __restrict__ out) {
  const int u0 = blockIdx.x * UCH + threadIdx.x * 4;   // first unit of this thread
  f32x4 g0[4], g1[4], bs[4];
#pragma unroll
  for (int q = 0; q < 4; ++q) {
    const int u = u0 + q * 1024;
    g0[q] = *(const f32x4*)(G + u);
    g1[q] = *(const f32x4*)(G + UNITSd + u);
    bs[q] = *(const f32x4*)(bias + u);
  }
  const int b0 = blockIdx.y * NB;
  float* outp = out + (size_t)b0 * UNITSd + u0;
  for (int k = 0; k < NB; ++k) {
    const f32x2 x = *(const f32x2*)(inputs + (b0 + k) * 2);
#pragma unroll
    for (int q = 0; q < 4; ++q) {
      f32x4 r;
      r.x = fmaxf(fmaf(x.y, g1[q].x, fmaf(x.x, g0[q].x, bs[q].x)), 0.f);
      r.y = fmaxf(fmaf(x.y, g1[q].y, fmaf(x.x, g0[q].y, bs[q].y)), 0.f);
      r.z = fmaxf(fmaf(x.y, g1[q].z, fmaf(x.x, g0[q].z, bs[q].z)), 0.f);
      r.w = fmaxf(fmaf(x.y, g1[q].w, fmaf(x.x, g0[q].w, bs[q].w)), 0.f);
      __builtin_nontemporal_store(r, (f32x4*)(outp + q * 1024));
    }
    outp += UNITSd;
  }
}

// ---------------------------------------------------------------------------
// Fallback (only if ws_size < 512 KiB): recompute this thread's G in prologue
// ---------------------------------------------------------------------------
__global__ __launch_bounds__(256) void td_fused(
    const float* __restrict__ inputs, const float* __restrict__ core1,
    const float* __restrict__ core2, const float* __restrict__ bias,
    float* __restrict__ out) {
  const int u = blockIdx.x * 1024 + threadIdx.x * 4;
  const int a = u >> 8;
  const int c = u & 255;   // c..c+3 all within same a (256 % 4 == 0)
  float s[BONDd];
#pragma unroll
  for (int p = 0; p < BONDd; ++p)
    s[p] = core1[a * BONDd + p] + core1[S0d * BONDd + a * BONDd + p];
  float g0[4], g1[4];
#pragma unroll
  for (int cc = 0; cc < 4; ++cc) {
    float a0 = 0.f, a1 = 0.f;
#pragma unroll
    for (int p = 0; p < BONDd; ++p) {
      a0 = fmaf(s[p], core2[(c + cc) * BONDd + p], a0);
      a1 = fmaf(s[p], core2[S1d * BONDd + (c + cc) * BONDd + p], a1);
    }
    g0[cc] = a0; g1[cc] = a1;
  }
  const f32x4 bs = *(const f32x4*)(bias + u);
  const int b0 = blockIdx.y * 64;
  float* outp = out + (size_t)b0 * UNITSd + u;
#pragma unroll 4
  for (int k = 0; k < 64; ++k) {
    const f32x2 x = *(const f32x2*)(inputs + (b0 + k) * 2);
    f32x4 r;
    r.x = fmaxf(fmaf(x.y, g1[0], fmaf(x.x, g0[0], bs.x)), 0.f);
    r.y = fmaxf(fmaf(x.y, g1[1], fmaf(x.x, g0[1], bs.y)), 0.f);
    r.z = fmaxf(fmaf(x.y, g1[2], fmaf(x.x, g0[2], bs.z)), 0.f);
    r.w = fmaxf(fmaf(x.y, g1[3], fmaf(x.x, g0[3], bs.w)), 0.f);
    *(f32x4*)outp = r;
    outp += UNITSd;
  }
}

extern "C" void kernel_launch(void* const* d_in, const int* in_sizes, int n_in,
                              void* d_out, int out_size, void* d_ws, size_t ws_size,
                              hipStream_t stream) {
  const float* inputs = (const float*)d_in[0];  // (2048, 2)
  const float* core1  = (const float*)d_in[1];  // (2, 256, 32)
  const float* core2  = (const float*)d_in[2];  // (2, 256, 32)
  const float* bias   = (const float*)d_in[3];  // (256, 256)
  float* out = (float*)d_out;                   // (2048, 65536)

  const size_t g_bytes = (size_t)2 * UNITSd * sizeof(float);
  if (ws_size >= g_bytes) {
    float* G = (float*)d_ws;
    precompute_G<<<UNITSd / 256, 256, 0, stream>>>(core1, core2, G);
    td_tile<<<dim3(UNITSd / UCH, BATCHd / NB), 256, 0, stream>>>(
        inputs, G, bias, out);
  } else {
    td_fused<<<dim3(UNITSd / 1024, BATCHd / 64), 256, 0, stream>>>(
        inputs, core1, core2, bias, out);
  }
}

// Round 5
// 117.044 us; speedup vs baseline: 1.0196x; 1.0196x over previous
//
#include <hip/hip_runtime.h>

// Problem constants (from reference)
#define S0d   256
#define S1d   256
#define BONDd 32
#define BATCHd 2048
#define UNITSd 65536        // S0 * S1
#define ROWS  4             // batch rows per block

typedef float f32x4 __attribute__((ext_vector_type(4)));
typedef float f32x2 __attribute__((ext_vector_type(2)));

// ---------------------------------------------------------------------------
// Kernel A: G_j[a*256+c] = sum_p (core1[0,a,p]+core1[1,a,p]) * core2[j,c,p]
// G layout in d_ws: G0[65536] then G1[65536]
// ---------------------------------------------------------------------------
__global__ __launch_bounds__(256) void precompute_G(
    const float* __restrict__ core1, const float* __restrict__ core2,
    float* __restrict__ G) {
  const int u = blockIdx.x * 256 + threadIdx.x;   // 0..65535
  const int a = u >> 8;
  const int c = u & 255;
  const f32x4* c10 = (const f32x4*)(core1 + a * BONDd);                 // core1[0,a,:]
  const f32x4* c11 = (const f32x4*)(core1 + S0d * BONDd + a * BONDd);   // core1[1,a,:]
  const f32x4* r0  = (const f32x4*)(core2 + c * BONDd);                 // core2[0,c,:]
  const f32x4* r1  = (const f32x4*)(core2 + S1d * BONDd + c * BONDd);   // core2[1,c,:]
  float acc0 = 0.f, acc1 = 0.f;
#pragma unroll
  for (int q = 0; q < BONDd / 4; ++q) {
    f32x4 x = c10[q], y = c11[q];
    f32x4 s = x + y;
    f32x4 v0 = r0[q], v1 = r1[q];
    acc0 = fmaf(s.x, v0.x, fmaf(s.y, v0.y, fmaf(s.z, v0.z, fmaf(s.w, v0.w, acc0))));
    acc1 = fmaf(s.x, v1.x, fmaf(s.y, v1.y, fmaf(s.z, v1.z, fmaf(s.w, v1.w, acc1))));
  }
  G[u] = acc0;
  G[UNITSd + u] = acc1;
}

// ---------------------------------------------------------------------------
// Kernel B (row-linear, 4 rows/block): block handles ROWS full batch rows.
// Each iteration loads one (g0,g1,bias) chunk into registers and stores it
// to ROWS linearly-advancing row streams. Read traffic = td_row / ROWS,
// write pattern identical to td_row (the R3 winner).
// ---------------------------------------------------------------------------
__global__ __launch_bounds__(256) void td_row4(
    const float* __restrict__ inputs, const float* __restrict__ G,
    const float* __restrict__ bias, float* __restrict__ out) {
  const int b0 = blockIdx.x * ROWS;
  f32x2 x[ROWS];
#pragma unroll
  for (int r = 0; r < ROWS; ++r)
    x[r] = *(const f32x2*)(inputs + (b0 + r) * 2);
  float* outp = out + (size_t)b0 * UNITSd;
  const int base = threadIdx.x * 4;
#pragma unroll 4
  for (int it = 0; it < UNITSd / 1024; ++it) {
    const int u = it * 1024 + base;
    const f32x4 g0 = *(const f32x4*)(G + u);
    const f32x4 g1 = *(const f32x4*)(G + UNITSd + u);
    const f32x4 bs = *(const f32x4*)(bias + u);
#pragma unroll
    for (int r = 0; r < ROWS; ++r) {
      f32x4 v;
      v.x = fmaxf(fmaf(x[r].y, g1.x, fmaf(x[r].x, g0.x, bs.x)), 0.f);
      v.y = fmaxf(fmaf(x[r].y, g1.y, fmaf(x[r].x, g0.y, bs.y)), 0.f);
      v.z = fmaxf(fmaf(x[r].y, g1.z, fmaf(x[r].x, g0.z, bs.z)), 0.f);
      v.w = fmaxf(fmaf(x[r].y, g1.w, fmaf(x[r].x, g0.w, bs.w)), 0.f);
      __builtin_nontemporal_store(v, (f32x4*)(outp + (size_t)r * UNITSd + u));
    }
  }
}

// ---------------------------------------------------------------------------
// Fallback (only if ws_size < 512 KiB): recompute this thread's G in prologue
// ---------------------------------------------------------------------------
__global__ __launch_bounds__(256) void td_fused(
    const float* __restrict__ inputs, const float* __restrict__ core1,
    const float* __restrict__ core2, const float* __restrict__ bias,
    float* __restrict__ out) {
  const int u = blockIdx.x * 1024 + threadIdx.x * 4;
  const int a = u >> 8;
  const int c = u & 255;   // c..c+3 all within same a (256 % 4 == 0)
  float s[BONDd];
#pragma unroll
  for (int p = 0; p < BONDd; ++p)
    s[p] = core1[a * BONDd + p] + core1[S0d * BONDd + a * BONDd + p];
  float g0[4], g1[4];
#pragma unroll
  for (int cc = 0; cc < 4; ++cc) {
    float a0 = 0.f, a1 = 0.f;
#pragma unroll
    for (int p = 0; p < BONDd; ++p) {
      a0 = fmaf(s[p], core2[(c + cc) * BONDd + p], a0);
      a1 = fmaf(s[p], core2[S1d * BONDd + (c + cc) * BONDd + p], a1);
    }
    g0[cc] = a0; g1[cc] = a1;
  }
  const f32x4 bs = *(const f32x4*)(bias + u);
  const int b0 = blockIdx.y * 64;
  float* outp = out + (size_t)b0 * UNITSd + u;
#pragma unroll 4
  for (int k = 0; k < 64; ++k) {
    const f32x2 x = *(const f32x2*)(inputs + (b0 + k) * 2);
    f32x4 r;
    r.x = fmaxf(fmaf(x.y, g1[0], fmaf(x.x, g0[0], bs.x)), 0.f);
    r.y = fmaxf(fmaf(x.y, g1[1], fmaf(x.x, g0[1], bs.y)), 0.f);
    r.z = fmaxf(fmaf(x.y, g1[2], fmaf(x.x, g0[2], bs.z)), 0.f);
    r.w = fmaxf(fmaf(x.y, g1[3], fmaf(x.x, g0[3], bs.w)), 0.f);
    *(f32x4*)outp = r;
    outp += UNITSd;
  }
}

extern "C" void kernel_launch(void* const* d_in, const int* in_sizes, int n_in,
                              void* d_out, int out_size, void* d_ws, size_t ws_size,
                              hipStream_t stream) {
  const float* inputs = (const float*)d_in[0];  // (2048, 2)
  const float* core1  = (const float*)d_in[1];  // (2, 256, 32)
  const float* core2  = (const float*)d_in[2];  // (2, 256, 32)
  const float* bias   = (const float*)d_in[3];  // (256, 256)
  float* out = (float*)d_out;                   // (2048, 65536)

  const size_t g_bytes = (size_t)2 * UNITSd * sizeof(float);
  if (ws_size >= g_bytes) {
    float* G = (float*)d_ws;
    precompute_G<<<UNITSd / 256, 256, 0, stream>>>(core1, core2, G);
    td_row4<<<BATCHd / ROWS, 256, 0, stream>>>(inputs, G, bias, out);
  } else {
    td_fused<<<dim3(UNITSd / 1024, BATCHd / 64), 256, 0, stream>>>(
        inputs, core1, core2, bias, out);
  }
}

// Round 6
// 109.279 us; speedup vs baseline: 1.0920x; 1.0711x over previous
//
#include <hip/hip_runtime.h>

// Problem constants (from reference)
#define S0d   256
#define S1d   256
#define BONDd 32
#define BATCHd 2048
#define UNITSd 65536        // S0 * S1

typedef float f32x4 __attribute__((ext_vector_type(4)));
typedef float f32x2 __attribute__((ext_vector_type(2)));

// ---------------------------------------------------------------------------
// Kernel A: G_j[a*256+c] = sum_p (core1[0,a,p]+core1[1,a,p]) * core2[j,c,p]
// G layout in d_ws: G0[65536] then G1[65536]
// ---------------------------------------------------------------------------
__global__ __launch_bounds__(256) void precompute_G(
    const float* __restrict__ core1, const float* __restrict__ core2,
    float* __restrict__ G) {
  const int u = blockIdx.x * 256 + threadIdx.x;   // 0..65535
  const int a = u >> 8;
  const int c = u & 255;
  const f32x4* c10 = (const f32x4*)(core1 + a * BONDd);                 // core1[0,a,:]
  const f32x4* c11 = (const f32x4*)(core1 + S0d * BONDd + a * BONDd);   // core1[1,a,:]
  const f32x4* r0  = (const f32x4*)(core2 + c * BONDd);                 // core2[0,c,:]
  const f32x4* r1  = (const f32x4*)(core2 + S1d * BONDd + c * BONDd);   // core2[1,c,:]
  float acc0 = 0.f, acc1 = 0.f;
#pragma unroll
  for (int q = 0; q < BONDd / 4; ++q) {
    f32x4 x = c10[q], y = c11[q];
    f32x4 s = x + y;
    f32x4 v0 = r0[q], v1 = r1[q];
    acc0 = fmaf(s.x, v0.x, fmaf(s.y, v0.y, fmaf(s.z, v0.z, fmaf(s.w, v0.w, acc0))));
    acc1 = fmaf(s.x, v1.x, fmaf(s.y, v1.y, fmaf(s.z, v1.z, fmaf(s.w, v1.w, acc1))));
  }
  G[u] = acc0;
  G[UNITSd + u] = acc1;
}

// ---------------------------------------------------------------------------
// Kernel B (wave-sequential + software pipeline): block b owns row b.
// Wave w owns the contiguous 64 KiB segment [w*16384, (w+1)*16384) floats,
// so every wave's successive 1 KiB store bursts are strictly sequential.
// G/bias loads for iteration it+1 are issued before the store of it, so
// NT stores never wait on same-iteration L2 loads.
// ---------------------------------------------------------------------------
__global__ __launch_bounds__(256) void td_wave(
    const float* __restrict__ inputs, const float* __restrict__ G,
    const float* __restrict__ bias, float* __restrict__ out) {
  const int b = blockIdx.x;
  const f32x2 x = *(const f32x2*)(inputs + b * 2);   // uniform per block
  const int wave = threadIdx.x >> 6;
  const int lane = threadIdx.x & 63;
  const int u0 = wave * (UNITSd / 4) + lane * 4;     // wave's segment start
  const float* gp0 = G + u0;
  const float* gp1 = G + UNITSd + u0;
  const float* bp  = bias + u0;
  float* outp = out + (size_t)b * UNITSd + u0;

  f32x4 g0n = *(const f32x4*)(gp0);
  f32x4 g1n = *(const f32x4*)(gp1);
  f32x4 bsn = *(const f32x4*)(bp);
#pragma unroll 4
  for (int it = 0; it < 63; ++it) {
    const f32x4 g0 = g0n, g1 = g1n, bs = bsn;
    g0n = *(const f32x4*)(gp0 + (it + 1) * 256);
    g1n = *(const f32x4*)(gp1 + (it + 1) * 256);
    bsn = *(const f32x4*)(bp  + (it + 1) * 256);
    f32x4 r;
    r.x = fmaxf(fmaf(x.y, g1.x, fmaf(x.x, g0.x, bs.x)), 0.f);
    r.y = fmaxf(fmaf(x.y, g1.y, fmaf(x.x, g0.y, bs.y)), 0.f);
    r.z = fmaxf(fmaf(x.y, g1.z, fmaf(x.x, g0.z, bs.z)), 0.f);
    r.w = fmaxf(fmaf(x.y, g1.w, fmaf(x.x, g0.w, bs.w)), 0.f);
    __builtin_nontemporal_store(r, (f32x4*)(outp + it * 256));
  }
  {  // epilogue it = 63
    f32x4 r;
    r.x = fmaxf(fmaf(x.y, g1n.x, fmaf(x.x, g0n.x, bsn.x)), 0.f);
    r.y = fmaxf(fmaf(x.y, g1n.y, fmaf(x.x, g0n.y, bsn.y)), 0.f);
    r.z = fmaxf(fmaf(x.y, g1n.z, fmaf(x.x, g0n.z, bsn.z)), 0.f);
    r.w = fmaxf(fmaf(x.y, g1n.w, fmaf(x.x, g0n.w, bsn.w)), 0.f);
    __builtin_nontemporal_store(r, (f32x4*)(outp + 63 * 256));
  }
}

// ---------------------------------------------------------------------------
// Fallback (only if ws_size < 512 KiB): recompute this thread's G in prologue
// ---------------------------------------------------------------------------
__global__ __launch_bounds__(256) void td_fused(
    const float* __restrict__ inputs, const float* __restrict__ core1,
    const float* __restrict__ core2, const float* __restrict__ bias,
    float* __restrict__ out) {
  const int u = blockIdx.x * 1024 + threadIdx.x * 4;
  const int a = u >> 8;
  const int c = u & 255;   // c..c+3 all within same a (256 % 4 == 0)
  float s[BONDd];
#pragma unroll
  for (int p = 0; p < BONDd; ++p)
    s[p] = core1[a * BONDd + p] + core1[S0d * BONDd + a * BONDd + p];
  float g0[4], g1[4];
#pragma unroll
  for (int cc = 0; cc < 4; ++cc) {
    float a0 = 0.f, a1 = 0.f;
#pragma unroll
    for (int p = 0; p < BONDd; ++p) {
      a0 = fmaf(s[p], core2[(c + cc) * BONDd + p], a0);
      a1 = fmaf(s[p], core2[S1d * BONDd + (c + cc) * BONDd + p], a1);
    }
    g0[cc] = a0; g1[cc] = a1;
  }
  const f32x4 bs = *(const f32x4*)(bias + u);
  const int b0 = blockIdx.y * 64;
  float* outp = out + (size_t)b0 * UNITSd + u;
#pragma unroll 4
  for (int k = 0; k < 64; ++k) {
    const f32x2 x = *(const f32x2*)(inputs + (b0 + k) * 2);
    f32x4 r;
    r.x = fmaxf(fmaf(x.y, g1[0], fmaf(x.x, g0[0], bs.x)), 0.f);
    r.y = fmaxf(fmaf(x.y, g1[1], fmaf(x.x, g0[1], bs.y)), 0.f);
    r.z = fmaxf(fmaf(x.y, g1[2], fmaf(x.x, g0[2], bs.z)), 0.f);
    r.w = fmaxf(fmaf(x.y, g1[3], fmaf(x.x, g0[3], bs.w)), 0.f);
    *(f32x4*)outp = r;
    outp += UNITSd;
  }
}

extern "C" void kernel_launch(void* const* d_in, const int* in_sizes, int n_in,
                              void* d_out, int out_size, void* d_ws, size_t ws_size,
                              hipStream_t stream) {
  const float* inputs = (const float*)d_in[0];  // (2048, 2)
  const float* core1  = (const float*)d_in[1];  // (2, 256, 32)
  const float* core2  = (const float*)d_in[2];  // (2, 256, 32)
  const float* bias   = (const float*)d_in[3];  // (256, 256)
  float* out = (float*)d_out;                   // (2048, 65536)

  const size_t g_bytes = (size_t)2 * UNITSd * sizeof(float);
  if (ws_size >= g_bytes) {
    float* G = (float*)d_ws;
    precompute_G<<<UNITSd / 256, 256, 0, stream>>>(core1, core2, G);
    td_wave<<<BATCHd, 256, 0, stream>>>(inputs, G, bias, out);
  } else {
    td_fused<<<dim3(UNITSd / 1024, BATCHd / 64), 256, 0, stream>>>(
        inputs, core1, core2, bias, out);
  }
}